// Round 8
// baseline (85.610 us; speedup 1.0000x reference)
//
#include <hip/hip_runtime.h>

// NestedFormula: DEPTH=4, V=4, B=131072. n1=125, n2=25, n3=5, n4=1.
//
// R8 = R7 structure with E=4 elements/thread (was 2):
//  - 5-way split by depth-3 subtree, r = threadIdx>>6 (wave-uniform ->
//    zero divergence, params scalar-loaded)
//  - 4 independent dep chains/thread hide the mul->exp->fma trans latency
//    (R7 vs R4 showed per-thread ILP, not wave count, is the lever)
//  - scalar param loads amortized over 4 elements
//  - LDS reduce (5KB), no atomics, no memset dispatch
// 512 blocks x 5 waves = 2560 waves (2.5/SIMD, grid-limited; ~10 indep
// chains per SIMD). Body ~18KB: fits 32KB I$.

#define VV 4
#define E  4

__device__ __forceinline__ void f1_evalE(int n1, const float lx[E][VV],
    const float* __restrict__ lam0, const float* __restrict__ lam1,
    const float* __restrict__ pow1, float f[E])
{
    const float l0 = lam0[n1];
#pragma unroll
    for (int e = 0; e < E; ++e) f[e] = l0;
#pragma unroll
    for (int v = 0; v < VV; ++v) {
        const float p = pow1[n1 * VV + v];
        const float l = lam1[n1 * VV + v];
#pragma unroll
        for (int e = 0; e < E; ++e)
            f[e] = fmaf(l, __builtin_amdgcn_exp2f(p * lx[e][v]), f[e]);
    }
}

__device__ __forceinline__ void f2_evalE(int n2, const float lx[E][VV],
    const float* __restrict__ lam0, const float* __restrict__ lam1,
    const float* __restrict__ pow1, const float* __restrict__ lam2,
    const float* __restrict__ pow2, float f[E])
{
    float acc[E];
#pragma unroll
    for (int e = 0; e < E; ++e) acc[e] = 0.f;
#pragma unroll
    for (int c1 = 0; c1 < VV; ++c1) {
        float f1[E];
        f1_evalE(n2 * (VV + 1) + c1, lx, lam0, lam1, pow1, f1);
        const float l = lam2[n2 * VV + c1];
        const float p = pow2[n2 * VV + c1];
#pragma unroll
        for (int e = 0; e < E; ++e)
            acc[e] = fmaf(l * __builtin_amdgcn_exp2f(p * lx[e][c1]), f1[e], acc[e]);
    }
    float lst[E];
    f1_evalE(n2 * (VV + 1) + VV, lx, lam0, lam1, pow1, lst);
#pragma unroll
    for (int e = 0; e < E; ++e) f[e] = acc[e] + lst[e];
}

__device__ __forceinline__ void f3_evalE(int n3, const float lx[E][VV],
    const float* __restrict__ lam0, const float* __restrict__ lam1,
    const float* __restrict__ pow1, const float* __restrict__ lam2,
    const float* __restrict__ pow2, const float* __restrict__ lam3,
    const float* __restrict__ pow3, float f[E])
{
    float acc[E];
#pragma unroll
    for (int e = 0; e < E; ++e) acc[e] = 0.f;
#pragma unroll
    for (int c2 = 0; c2 < VV; ++c2) {
        float f2[E];
        f2_evalE(n3 * (VV + 1) + c2, lx, lam0, lam1, pow1, lam2, pow2, f2);
        const float l = lam3[n3 * VV + c2];
        const float p = pow3[n3 * VV + c2];
#pragma unroll
        for (int e = 0; e < E; ++e)
            acc[e] = fmaf(l * __builtin_amdgcn_exp2f(p * lx[e][c2]), f2[e], acc[e]);
    }
    float lst[E];
    f2_evalE(n3 * (VV + 1) + VV, lx, lam0, lam1, pow1, lam2, pow2, lst);
#pragma unroll
    for (int e = 0; e < E; ++e) f[e] = acc[e] + lst[e];
}

__global__ __launch_bounds__(320) void nested_formula_r8(
    const float4* __restrict__ x,      // (B, 4)
    const float*  __restrict__ lam0,   // (125,)
    const float*  __restrict__ lam1,   // (125,4)
    const float*  __restrict__ pow1,   // (125,4)
    const float*  __restrict__ lam2,   // (25,4)
    const float*  __restrict__ pow2,   // (25,4)
    const float*  __restrict__ lam3,   // (5,4)
    const float*  __restrict__ pow3,   // (5,4)
    const float*  __restrict__ lam4,   // (1,4)
    const float*  __restrict__ pow4,   // (1,4)
    float* __restrict__ out,           // (B,)
    int B)
{
    const int lane = threadIdx.x & 63;
    const int r    = threadIdx.x >> 6;              // 0..4, wave-uniform
    const int base = blockIdx.x * (64 * E) + lane;  // elements base + 64*e

    __shared__ float red[5][64 * E];                // 5KB

    float lx[E][VV];
#pragma unroll
    for (int e = 0; e < E; ++e) {
        const int b = base + 64 * e;
        const float4 xv = x[min(b, B - 1)];
        lx[e][0] = __builtin_amdgcn_logf(xv.x);
        lx[e][1] = __builtin_amdgcn_logf(xv.y);
        lx[e][2] = __builtin_amdgcn_logf(xv.z);
        lx[e][3] = __builtin_amdgcn_logf(xv.w);
    }

    float f3[E];
    f3_evalE(r, lx, lam0, lam1, pow1, lam2, pow2, lam3, pow3, f3);

    float part[E];
    if (r < 4) {                                    // uniform branch
        const float l4 = lam4[r];
        const float p4 = pow4[r];
#pragma unroll
        for (int e = 0; e < E; ++e) {
            const float lxr = (r == 0) ? lx[e][0] : (r == 1) ? lx[e][1]
                            : (r == 2) ? lx[e][2] : lx[e][3];
            part[e] = l4 * __builtin_amdgcn_exp2f(p4 * lxr) * f3[e];
        }
    } else {                                        // last_subformula: weight 1
#pragma unroll
        for (int e = 0; e < E; ++e) part[e] = f3[e];
    }

#pragma unroll
    for (int e = 0; e < E; ++e) red[r][lane + 64 * e] = part[e];
    __syncthreads();

    if (r == 0) {
#pragma unroll
        for (int e = 0; e < E; ++e) {
            const int i = lane + 64 * e;
            const int b = base + 64 * e;
            float s = ((red[0][i] + red[1][i]) + (red[2][i] + red[3][i]))
                      + red[4][i];
            if (b < B) out[b] = s;
        }
    }
}

extern "C" void kernel_launch(void* const* d_in, const int* in_sizes, int n_in,
                              void* d_out, int out_size, void* d_ws, size_t ws_size,
                              hipStream_t stream) {
    const float4* x    = (const float4*)d_in[0];
    const float*  lam0 = (const float*)d_in[1];
    const float*  lam1 = (const float*)d_in[2];
    const float*  pow1 = (const float*)d_in[3];
    const float*  lam2 = (const float*)d_in[4];
    const float*  pow2 = (const float*)d_in[5];
    const float*  lam3 = (const float*)d_in[6];
    const float*  pow3 = (const float*)d_in[7];
    const float*  lam4 = (const float*)d_in[8];
    const float*  pow4 = (const float*)d_in[9];
    float* out = (float*)d_out;

    int B = in_sizes[0] / 4;  // x is (B, 4)
    dim3 block(320, 1, 1);                      // 5 waves: one per subtree
    dim3 grid((B + 64 * E - 1) / (64 * E), 1);  // 512 blocks at B=131072
    nested_formula_r8<<<grid, block, 0, stream>>>(
        x, lam0, lam1, pow1, lam2, pow2, lam3, pow3, lam4, pow4, out, B);
}

// Round 9
// 83.600 us; speedup vs baseline: 1.0240x; 1.0240x over previous
//
#include <hip/hip_runtime.h>

// NestedFormula: DEPTH=4, V=4, B=131072. n1=125, n2=25, n3=5, n4=1.
//
// R9 = R7 (best: 5-way subtree split, E=2, LDS reduce) + ALL params staged
// to LDS as interleaved (lam,pow) float2 pairs, read with wave-uniform
// ds_read_b64 at compile-time immediate offsets (broadcast, bank-conflict
// free). Theory: the flat ~18us across R4/R7/R8 (different ILP/TLP mixes)
// is s_waitcnt lgkmcnt(0) drains on scalar param loads (SGPR budget caps
// prefetch at ~10 terms). LDS reads prefetch ~30 deep via VGPRs with
// fine-grained lgkmcnt -> stalls should vanish.
// LDS: 5504B params + 2560B reduce = 8KB. 1024 blocks x 5 waves.

#define VV 4

// LDS param layout (float indices; even offsets -> 8B-aligned float2)
#define L0_OFF  0      // lam0[125] (padded region to 128)
#define LP1_OFF 128    // (lam1,pow1)[125*4] pairs
#define LP2_OFF 1128   // (lam2,pow2)[25*4]  pairs
#define LP3_OFF 1328   // (lam3,pow3)[5*4]   pairs
#define LP4_OFF 1368   // (lam4,pow4)[4]     pairs
#define P_TOTAL 1376

__device__ __forceinline__ float2 ldlp(const float* sp, int off) {
    return *(const float2*)(sp + off);     // off even => 8B aligned
}

__device__ __forceinline__ void f1_eval2(const float* sp, int n1,
    const float lxA[VV], const float lxB[VV], float& fA, float& fB)
{
    float a = sp[L0_OFF + n1], b = a;
#pragma unroll
    for (int v = 0; v < VV; ++v) {
        const float2 lp = ldlp(sp, LP1_OFF + n1 * 8 + v * 2);
        a = fmaf(lp.x, __builtin_amdgcn_exp2f(lp.y * lxA[v]), a);
        b = fmaf(lp.x, __builtin_amdgcn_exp2f(lp.y * lxB[v]), b);
    }
    fA = a; fB = b;
}

__device__ __forceinline__ void f2_eval2(const float* sp, int n2,
    const float lxA[VV], const float lxB[VV], float& fA, float& fB)
{
    float accA = 0.f, accB = 0.f;
#pragma unroll
    for (int c1 = 0; c1 < VV; ++c1) {
        float f1A, f1B;
        f1_eval2(sp, n2 * (VV + 1) + c1, lxA, lxB, f1A, f1B);
        const float2 lp = ldlp(sp, LP2_OFF + n2 * 8 + c1 * 2);
        accA = fmaf(lp.x * __builtin_amdgcn_exp2f(lp.y * lxA[c1]), f1A, accA);
        accB = fmaf(lp.x * __builtin_amdgcn_exp2f(lp.y * lxB[c1]), f1B, accB);
    }
    float lA, lB;
    f1_eval2(sp, n2 * (VV + 1) + VV, lxA, lxB, lA, lB);
    fA = accA + lA; fB = accB + lB;
}

__device__ __forceinline__ void f3_eval2(const float* sp, int n3,
    const float lxA[VV], const float lxB[VV], float& fA, float& fB)
{
    float accA = 0.f, accB = 0.f;
#pragma unroll
    for (int c2 = 0; c2 < VV; ++c2) {
        float f2A, f2B;
        f2_eval2(sp, n3 * (VV + 1) + c2, lxA, lxB, f2A, f2B);
        const float2 lp = ldlp(sp, LP3_OFF + n3 * 8 + c2 * 2);
        accA = fmaf(lp.x * __builtin_amdgcn_exp2f(lp.y * lxA[c2]), f2A, accA);
        accB = fmaf(lp.x * __builtin_amdgcn_exp2f(lp.y * lxB[c2]), f2B, accB);
    }
    float lA, lB;
    f2_eval2(sp, n3 * (VV + 1) + VV, lxA, lxB, lA, lB);
    fA = accA + lA; fB = accB + lB;
}

__global__ __launch_bounds__(320) void nested_formula_r9(
    const float4* __restrict__ x,      // (B, 4)
    const float*  __restrict__ lam0,   // (125,)
    const float*  __restrict__ lam1,   // (125,4)
    const float*  __restrict__ pow1,   // (125,4)
    const float*  __restrict__ lam2,   // (25,4)
    const float*  __restrict__ pow2,   // (25,4)
    const float*  __restrict__ lam3,   // (5,4)
    const float*  __restrict__ pow3,   // (5,4)
    const float*  __restrict__ lam4,   // (1,4)
    const float*  __restrict__ pow4,   // (1,4)
    float* __restrict__ out,           // (B,)
    int B)
{
    __shared__ float sp[P_TOTAL];
    __shared__ float red[5][128];

    const int tid  = threadIdx.x;
    const int lane = tid & 63;
    const int r    = tid >> 6;                   // 0..4, wave-uniform
    const int b0   = blockIdx.x * 128 + lane;
    const int b1   = b0 + 64;

    // ---- cooperative param staging (interleave lam,pow pairs) ----
    for (int i = tid; i < 125; i += 320) sp[L0_OFF + i] = lam0[i];
    for (int i = tid; i < 500; i += 320) {
        sp[LP1_OFF + 2 * i]     = lam1[i];
        sp[LP1_OFF + 2 * i + 1] = pow1[i];
    }
    if (tid < 100) {
        sp[LP2_OFF + 2 * tid]     = lam2[tid];
        sp[LP2_OFF + 2 * tid + 1] = pow2[tid];
    }
    if (tid < 20) {
        sp[LP3_OFF + 2 * tid]     = lam3[tid];
        sp[LP3_OFF + 2 * tid + 1] = pow3[tid];
    }
    if (tid < 4) {
        sp[LP4_OFF + 2 * tid]     = lam4[tid];
        sp[LP4_OFF + 2 * tid + 1] = pow4[tid];
    }

    const float4 xa = x[min(b0, B - 1)];
    const float4 xb = x[min(b1, B - 1)];
    const float lxA[VV] = { __builtin_amdgcn_logf(xa.x), __builtin_amdgcn_logf(xa.y),
                            __builtin_amdgcn_logf(xa.z), __builtin_amdgcn_logf(xa.w) };
    const float lxB[VV] = { __builtin_amdgcn_logf(xb.x), __builtin_amdgcn_logf(xb.y),
                            __builtin_amdgcn_logf(xb.z), __builtin_amdgcn_logf(xb.w) };

    __syncthreads();

    // ---- main: depth-3 subtree r ----
    float f3A, f3B;
    f3_eval2(sp, r, lxA, lxB, f3A, f3B);

    float pA, pB;
    if (r < 4) {                                  // uniform branch
        const float2 lp4 = ldlp(sp, LP4_OFF + r * 2);
        const float lxrA = (r == 0) ? lxA[0] : (r == 1) ? lxA[1]
                         : (r == 2) ? lxA[2] : lxA[3];
        const float lxrB = (r == 0) ? lxB[0] : (r == 1) ? lxB[1]
                         : (r == 2) ? lxB[2] : lxB[3];
        pA = lp4.x * __builtin_amdgcn_exp2f(lp4.y * lxrA) * f3A;
        pB = lp4.x * __builtin_amdgcn_exp2f(lp4.y * lxrB) * f3B;
    } else {                                      // last_subformula: weight 1
        pA = f3A;
        pB = f3B;
    }

    red[r][lane]      = pA;
    red[r][lane + 64] = pB;
    __syncthreads();

    if (r == 0) {
        float sA = ((red[0][lane] + red[1][lane]) +
                    (red[2][lane] + red[3][lane])) + red[4][lane];
        float sB = ((red[0][lane + 64] + red[1][lane + 64]) +
                    (red[2][lane + 64] + red[3][lane + 64])) + red[4][lane + 64];
        if (b0 < B) out[b0] = sA;
        if (b1 < B) out[b1] = sB;
    }
}

extern "C" void kernel_launch(void* const* d_in, const int* in_sizes, int n_in,
                              void* d_out, int out_size, void* d_ws, size_t ws_size,
                              hipStream_t stream) {
    const float4* x    = (const float4*)d_in[0];
    const float*  lam0 = (const float*)d_in[1];
    const float*  lam1 = (const float*)d_in[2];
    const float*  pow1 = (const float*)d_in[3];
    const float*  lam2 = (const float*)d_in[4];
    const float*  pow2 = (const float*)d_in[5];
    const float*  lam3 = (const float*)d_in[6];
    const float*  pow3 = (const float*)d_in[7];
    const float*  lam4 = (const float*)d_in[8];
    const float*  pow4 = (const float*)d_in[9];
    float* out = (float*)d_out;

    int B = in_sizes[0] / 4;  // x is (B, 4)
    dim3 block(320, 1, 1);                 // 5 waves: one per depth-3 subtree
    dim3 grid((B + 127) / 128, 1, 1);      // 1024 blocks at B=131072
    nested_formula_r9<<<grid, block, 0, stream>>>(
        x, lam0, lam1, pow1, lam2, pow2, lam3, pow3, lam4, pow4, out, B);
}